// Round 1
// baseline (281.844 us; speedup 1.0000x reference)
//
#include <hip/hip_runtime.h>

typedef __bf16 bf16x8 __attribute__((ext_vector_type(8)));
typedef float f32x4 __attribute__((ext_vector_type(4)));

// ---------------- ws layout (float offsets) ----------------
#define WS_ALLREPS 0         // 384*768
#define WS_APRIME  294912    // 384*768  (A + b_pair1)
#define WS_BMAT    589824    // 384*768
#define WS_RELUM1  884736    // 384*384
#define WS_RELUC1  1032192   // 384*384
#define WS_MS      1179648   // 384
#define WS_SSUM    1180032   // 384
#define WS_PF      1180416   // 384
#define WS_W2BF    1180800   // bf16[384*768] lives here

__device__ __forceinline__ bf16x8 cvt8(float4 a, float4 b) {
  bf16x8 v;
  v[0]=(__bf16)a.x; v[1]=(__bf16)a.y; v[2]=(__bf16)a.z; v[3]=(__bf16)a.w;
  v[4]=(__bf16)b.x; v[5]=(__bf16)b.y; v[6]=(__bf16)b.z; v[7]=(__bf16)b.w;
  return v;
}

// K1: build all_reps (f32) rows 0..383 and W2bf (bf16) rows 384..767
__global__ __launch_bounds__(256) void k_build(
    const float* __restrict__ seq, const float* __restrict__ spk_emb,
    const float* __restrict__ dummy, const float* __restrict__ W2,
    const int* __restrict__ seg, const int* __restrict__ mstart,
    const int* __restrict__ mend, const int* __restrict__ spk_ids,
    float* __restrict__ all_reps, __bf16* __restrict__ W2bf) {
  int r = blockIdx.x, t = threadIdx.x;
  if (r < 384) {
    if (r == 0) {
      #pragma unroll
      for (int e = 0; e < 3; ++e) { int k = t + 256*e; all_reps[k] = dummy[k]; }
    } else {
      int m = r - 1;
      int sg = seg[m], st = mstart[m], en = mend[m];
      int sp = spk_ids[sg*512 + st];
      const float* p1 = seq + (size_t)(sg*512 + st)*768;
      const float* p2 = seq + (size_t)(sg*512 + en)*768;
      const float* p3 = spk_emb + (size_t)sp*768;
      #pragma unroll
      for (int e = 0; e < 3; ++e) { int k = t + 256*e; all_reps[r*768+k] = p1[k]+p2[k]+p3[k]; }
    }
  } else {
    int h = r - 384;
    #pragma unroll
    for (int e = 0; e < 3; ++e) { int k = t + 256*e; W2bf[h*768+k] = (__bf16)W2[h*768+k]; }
  }
}

// K2: C = reps(384x768) @ Bop(768x2304); Bop columns: [A(768) | Bm(768) | m1(384) | c1(384)]
// tile 128x128, 256 thr (4 waves 2x2, wave 64x64), BK=32
__global__ __launch_bounds__(256) void k_gemmB(
    const float* __restrict__ reps, const float* __restrict__ W1,
    const float* __restrict__ Wm1, const float* __restrict__ Wc1,
    const float* __restrict__ b1, const float* __restrict__ bm1, const float* __restrict__ bc1,
    float* __restrict__ Aprime, float* __restrict__ Bmat,
    float* __restrict__ relu_m1, float* __restrict__ relu_c1) {
  __shared__ bf16x8 lA[128*4];
  __shared__ bf16x8 lB[128*4];
  int nt = blockIdx.x;
  int m0 = blockIdx.y * 128;
  int t = threadIdx.x;
  const float* src; int stride, coloff;
  if (nt < 6)       { src = W1  + (size_t)(nt*128)*1536;      stride = 1536; coloff = 0;   }
  else if (nt < 12) { src = W1  + (size_t)((nt-6)*128)*1536;  stride = 1536; coloff = 768; }
  else if (nt < 15) { src = Wm1 + (size_t)((nt-12)*128)*768;  stride = 768;  coloff = 0;   }
  else              { src = Wc1 + (size_t)((nt-15)*128)*768;  stride = 768;  coloff = 0;   }

  int w = t>>6, l = t&63;
  int wm = w&1, wn = w>>1;
  int lr = l&15, lg = l>>4;

  int r2 = t>>1, half = t&1;
  const float* pa_base = reps + (size_t)(m0+r2)*768 + half*16;
  const float* pb_base = src + (size_t)r2*stride + coloff + half*16;
  int c0 = half*2, c1 = half*2+1;
  int idxA0 = r2*4 + (c0 ^ (r2&3));
  int idxA1 = r2*4 + (c1 ^ (r2&3));

  f32x4 acc[4][4] = {};

  for (int ks = 0; ks < 24; ++ks) {
    int k0 = ks*32;
    {
      float4 f0 = *(const float4*)(pa_base + k0);
      float4 f1 = *(const float4*)(pa_base + k0 + 4);
      float4 f2 = *(const float4*)(pa_base + k0 + 8);
      float4 f3 = *(const float4*)(pa_base + k0 + 12);
      lA[idxA0] = cvt8(f0, f1);
      lA[idxA1] = cvt8(f2, f3);
      float4 g0 = *(const float4*)(pb_base + k0);
      float4 g1 = *(const float4*)(pb_base + k0 + 4);
      float4 g2 = *(const float4*)(pb_base + k0 + 8);
      float4 g3 = *(const float4*)(pb_base + k0 + 12);
      lB[idxA0] = cvt8(g0, g1);
      lB[idxA1] = cvt8(g2, g3);
    }
    __syncthreads();
    bf16x8 af[4], bfr[4];
    #pragma unroll
    for (int fa = 0; fa < 4; ++fa) { int row = wm*64 + fa*16 + lr; af[fa] = lA[row*4 + (lg ^ (row&3))]; }
    #pragma unroll
    for (int fb = 0; fb < 4; ++fb) { int row = wn*64 + fb*16 + lr; bfr[fb] = lB[row*4 + (lg ^ (row&3))]; }
    #pragma unroll
    for (int fa = 0; fa < 4; ++fa)
      #pragma unroll
      for (int fb = 0; fb < 4; ++fb)
        acc[fa][fb] = __builtin_amdgcn_mfma_f32_16x16x32_bf16(af[fa], bfr[fb], acc[fa][fb], 0, 0, 0);
    __syncthreads();
  }

  #pragma unroll
  for (int fa = 0; fa < 4; ++fa) {
    #pragma unroll
    for (int fb = 0; fb < 4; ++fb) {
      #pragma unroll
      for (int reg = 0; reg < 4; ++reg) {
        int m = m0 + wm*64 + fa*16 + lg*4 + reg;
        int nl = wn*64 + fb*16 + lr;
        float v = acc[fa][fb][reg];
        if (nt < 6)       { int n = nt*128 + nl;      Aprime[m*768+n]  = v + b1[n]; }
        else if (nt < 12) { int n = (nt-6)*128 + nl;  Bmat[m*768+n]    = v; }
        else if (nt < 15) { int n = (nt-12)*128 + nl; relu_m1[m*384+n] = fmaxf(v + bm1[n], 0.f); }
        else              { int n = (nt-15)*128 + nl; relu_c1[m*384+n] = fmaxf(v + bc1[n], 0.f); }
      }
    }
  }
}

// K3: ms chain: relu_m1(384x384) -> relu(@Wm2^T+bm2)(192) -> @Wm3+bm3 -> ms[384]
__global__ __launch_bounds__(192) void k_ms(
    const float* __restrict__ relu_m1, const float* __restrict__ Wm2,
    const float* __restrict__ bm2, const float* __restrict__ Wm3,
    const float* __restrict__ bm3, float* __restrict__ ms) {
  __shared__ float x[384];
  __shared__ float part[3];
  int r = blockIdx.x, t = threadIdx.x;
  x[t] = relu_m1[r*384 + t];
  x[t+192] = relu_m1[r*384 + t + 192];
  __syncthreads();
  float d = 0.f;
  const float4* wv = (const float4*)(Wm2 + (size_t)t*384);
  const float4* xv = (const float4*)x;
  for (int k = 0; k < 96; ++k) {
    float4 a = xv[k], b = wv[k];
    d += a.x*b.x + a.y*b.y + a.z*b.z + a.w*b.w;
  }
  float c = fmaxf(d + bm2[t], 0.f) * Wm3[t];
  c += __shfl_xor(c, 1);  c += __shfl_xor(c, 2);  c += __shfl_xor(c, 4);
  c += __shfl_xor(c, 8);  c += __shfl_xor(c, 16); c += __shfl_xor(c, 32);
  if ((t&63) == 0) part[t>>6] = c;
  __syncthreads();
  if (t == 0) ms[r] = part[0] + part[1] + part[2] + bm3[0];
}

// K4: pair scores, lower triangle. Grid (jb=48, ib=24), 512 thr (8 waves: 2p x 4h).
// Tile: 128 pairs (16 i x 8 j) x 384 h, K=768 in 24 steps of 32.
__global__ __launch_bounds__(512) void k_pair(
    const float* __restrict__ Aprime, const float* __restrict__ Bmat,
    const __bf16* __restrict__ W2bf, const float* __restrict__ b2,
    const float* __restrict__ w3, const float* __restrict__ b3,
    const float* __restrict__ ms, const int* __restrict__ lfirst,
    float* __restrict__ Ssum, float* __restrict__ Pf) {
  int jb = blockIdx.x, ib = blockIdx.y;
  if (jb > 2*ib + 1) return;       // block entirely above/on diagonal
  __shared__ bf16x8 lA[128*4];     // h1 tile [128p][32k], XOR-swizzled 16B chunks
  __shared__ bf16x8 lB[384*4];     // W2 tile [384h][32k], same swizzle
  __shared__ float score_lds[128][4];

  int t = threadIdx.x;
  int w = t>>6, l = t&63;
  int wp = w&1, wh = w>>1;
  int lr = l&15, lg = l>>4;
  int i0 = ib*16, j0 = jb*8;

  // staging coords: p = pair row (0..127), q = k-chunk (0..3)
  int p = t>>2, q = t&3;
  const float* pArow = Aprime + (size_t)(j0 + (p&7))*768 + q*8;
  const float* pBrow = Bmat   + (size_t)(i0 + (p>>3))*768 + q*8;
  int idxH = p*4 + (q ^ (p&3));
  const __bf16* pW0 = W2bf + (size_t)p*768       + q*8;
  const __bf16* pW1 = W2bf + (size_t)(p+128)*768 + q*8;
  const __bf16* pW2p = W2bf + (size_t)(p+256)*768 + q*8;
  int idxW0 = p*4       + (q ^ (p&3));
  int idxW1 = (p+128)*4 + (q ^ (p&3));
  int idxW2 = (p+256)*4 + (q ^ (p&3));

  // prologue prefetch (ks=0)
  float4 ga0 = *(const float4*)(pArow);
  float4 ga1 = *(const float4*)(pArow + 4);
  float4 gb0 = *(const float4*)(pBrow);
  float4 gb1 = *(const float4*)(pBrow + 4);
  bf16x8 gw0 = *(const bf16x8*)(pW0);
  bf16x8 gw1 = *(const bf16x8*)(pW1);
  bf16x8 gw2 = *(const bf16x8*)(pW2p);

  f32x4 acc[4][6] = {};

  for (int ks = 0; ks < 24; ++ks) {
    // write staged tile (h1 = relu(A'[j] + Bm[i]))
    {
      float4 r0, r1;
      r0.x = fmaxf(ga0.x + gb0.x, 0.f); r0.y = fmaxf(ga0.y + gb0.y, 0.f);
      r0.z = fmaxf(ga0.z + gb0.z, 0.f); r0.w = fmaxf(ga0.w + gb0.w, 0.f);
      r1.x = fmaxf(ga1.x + gb1.x, 0.f); r1.y = fmaxf(ga1.y + gb1.y, 0.f);
      r1.z = fmaxf(ga1.z + gb1.z, 0.f); r1.w = fmaxf(ga1.w + gb1.w, 0.f);
      lA[idxH] = cvt8(r0, r1);
      lB[idxW0] = gw0; lB[idxW1] = gw1; lB[idxW2] = gw2;
    }
    __syncthreads();
    if (ks < 23) {   // prefetch next K-step under the MFMAs
      int k0 = (ks+1)*32;
      ga0 = *(const float4*)(pArow + k0);
      ga1 = *(const float4*)(pArow + k0 + 4);
      gb0 = *(const float4*)(pBrow + k0);
      gb1 = *(const float4*)(pBrow + k0 + 4);
      gw0 = *(const bf16x8*)(pW0 + k0);
      gw1 = *(const bf16x8*)(pW1 + k0);
      gw2 = *(const bf16x8*)(pW2p + k0);
    }
    bf16x8 af[4], bfr[6];
    #pragma unroll
    for (int fp = 0; fp < 4; ++fp) { int row = wp*64 + fp*16 + lr; af[fp] = lA[row*4 + (lg ^ (row&3))]; }
    #pragma unroll
    for (int fh = 0; fh < 6; ++fh) { int row = wh*96 + fh*16 + lr; bfr[fh] = lB[row*4 + (lg ^ (row&3))]; }
    #pragma unroll
    for (int fp = 0; fp < 4; ++fp)
      #pragma unroll
      for (int fh = 0; fh < 6; ++fh)
        acc[fp][fh] = __builtin_amdgcn_mfma_f32_16x16x32_bf16(af[fp], bfr[fh], acc[fp][fh], 0, 0, 0);
    __syncthreads();
  }

  // epilogue 1: s_p += w3[h]*relu(C2 + b2[h]) over this wave's 96 h
  float sacc[4][4] = {};
  #pragma unroll
  for (int fh = 0; fh < 6; ++fh) {
    int hcol = wh*96 + fh*16 + lr;
    float bb = b2[hcol], ww = w3[hcol];
    #pragma unroll
    for (int fp = 0; fp < 4; ++fp)
      #pragma unroll
      for (int reg = 0; reg < 4; ++reg)
        sacc[fp][reg] += fmaxf(acc[fp][fh][reg] + bb, 0.f) * ww;
  }
  #pragma unroll
  for (int fp = 0; fp < 4; ++fp) {
    #pragma unroll
    for (int reg = 0; reg < 4; ++reg) {
      float v = sacc[fp][reg];
      v += __shfl_xor(v, 1); v += __shfl_xor(v, 2);
      v += __shfl_xor(v, 4); v += __shfl_xor(v, 8);
      if (lr == 0) score_lds[wp*64 + fp*16 + lg*4 + reg][wh] = v;
    }
  }
  __syncthreads();

  // epilogue 2: combine 4 h-waves, add b3, exp-sum per row i, pick Pf
  if (t < 128) {
    int pp = t;
    float s = score_lds[pp][0] + score_lds[pp][1] + score_lds[pp][2] + score_lds[pp][3] + b3[0];
    int i = i0 + (pp>>3), j = j0 + (pp&7);
    float e = 0.f;
    if (j < i) {
      float sm = s + ms[j];
      e = __expf(sm);
      if (j == lfirst[i-1]) Pf[i] = sm;
    }
    e += __shfl_xor(e, 1); e += __shfl_xor(e, 2); e += __shfl_xor(e, 4);
    if ((t&7) == 0) atomicAdd(&Ssum[i], e);
  }
}

// K5: char CE
__global__ __launch_bounds__(64) void k_ce(
    const float* __restrict__ relu_c1, const float* __restrict__ Wc2,
    const float* __restrict__ bc2, const int* __restrict__ label,
    float* __restrict__ out) {
  __shared__ float lg[18];
  int m = blockIdx.x, t = threadIdx.x;
  if (t < 18) {
    const float4* xv = (const float4*)(relu_c1 + (size_t)(m+1)*384);
    const float4* wv = (const float4*)(Wc2 + (size_t)t*384);
    float d = 0.f;
    for (int k = 0; k < 96; ++k) {
      float4 a = xv[k], b = wv[k];
      d += a.x*b.x + a.y*b.y + a.z*b.z + a.w*b.w;
    }
    lg[t] = d + bc2[t];
  }
  __syncthreads();
  if (t == 0) {
    float sum = 0.f;
    for (int c = 0; c < 18; ++c) sum += __expf(lg[c]);
    atomicAdd(out, __logf(sum) - lg[label[m]]);
  }
}

// K6: nll reduce
__global__ __launch_bounds__(384) void k_nll(
    const float* __restrict__ Ssum, const float* __restrict__ Pf,
    float* __restrict__ out) {
  int i = threadIdx.x;
  if (i >= 1) atomicAdd(out, __logf(Ssum[i]) - Pf[i]);
}

extern "C" void kernel_launch(void* const* d_in, const int* in_sizes, int n_in,
                              void* d_out, int out_size, void* d_ws, size_t ws_size,
                              hipStream_t stream) {
  (void)in_sizes; (void)n_in; (void)out_size; (void)ws_size;
  const float* seq   = (const float*)d_in[0];
  const float* spk   = (const float*)d_in[1];
  const float* dummy = (const float*)d_in[2];
  const float* W1    = (const float*)d_in[3];
  const float* b1    = (const float*)d_in[4];
  const float* W2    = (const float*)d_in[5];
  const float* b2    = (const float*)d_in[6];
  const float* W3    = (const float*)d_in[7];
  const float* b3    = (const float*)d_in[8];
  const float* Wm1   = (const float*)d_in[9];
  const float* bm1   = (const float*)d_in[10];
  const float* Wm2   = (const float*)d_in[11];
  const float* bm2   = (const float*)d_in[12];
  const float* Wm3   = (const float*)d_in[13];
  const float* bm3   = (const float*)d_in[14];
  const float* Wc1   = (const float*)d_in[15];
  const float* bc1   = (const float*)d_in[16];
  const float* Wc2   = (const float*)d_in[17];
  const float* bc2   = (const float*)d_in[18];
  const int* seg     = (const int*)d_in[19];
  const int* mstart  = (const int*)d_in[20];
  const int* mend    = (const int*)d_in[21];
  const int* spk_ids = (const int*)d_in[22];
  const int* lfirst  = (const int*)d_in[23];
  const int* clabel  = (const int*)d_in[25];

  float* ws = (float*)d_ws;
  float* all_reps = ws + WS_ALLREPS;
  float* Aprime   = ws + WS_APRIME;
  float* Bmat     = ws + WS_BMAT;
  float* relu_m1  = ws + WS_RELUM1;
  float* relu_c1  = ws + WS_RELUC1;
  float* msv      = ws + WS_MS;
  float* Ssum     = ws + WS_SSUM;
  float* Pf       = ws + WS_PF;
  __bf16* W2bf    = (__bf16*)(ws + WS_W2BF);
  float* out      = (float*)d_out;

  hipMemsetAsync(out, 0, sizeof(float), stream);
  hipMemsetAsync(Ssum, 0, 384*sizeof(float), stream);

  k_build<<<768, 256, 0, stream>>>(seq, spk, dummy, W2, seg, mstart, mend, spk_ids, all_reps, W2bf);
  k_gemmB<<<dim3(18,3), 256, 0, stream>>>(all_reps, W1, Wm1, Wc1, b1, bm1, bc1, Aprime, Bmat, relu_m1, relu_c1);
  k_ms<<<384, 192, 0, stream>>>(relu_m1, Wm2, bm2, Wm3, bm3, msv);
  k_pair<<<dim3(48,24), 512, 0, stream>>>(Aprime, Bmat, W2bf, b2, W3, b3, msv, lfirst, Ssum, Pf);
  k_ce<<<383, 64, 0, stream>>>(relu_c1, Wc2, bc2, clabel, out);
  k_nll<<<1, 384, 0, stream>>>(Ssum, Pf, out);
}

// Round 3
// 261.206 us; speedup vs baseline: 1.0790x; 1.0790x over previous
//
#include <hip/hip_runtime.h>

typedef __bf16 bf16x8 __attribute__((ext_vector_type(8)));
typedef float f32x4 __attribute__((ext_vector_type(4)));

// ---------------- ws layout (float offsets) ----------------
#define WS_ALLREPS 0         // 384*768
#define WS_APRIME  294912    // 384*768  (A + b_pair1)
#define WS_BMAT    589824    // 384*768
#define WS_RELUM1  884736    // 384*384
#define WS_RELUC1  1032192   // 384*384
#define WS_MS      1179648   // 384
#define WS_SSUM    1180032   // 384
#define WS_PF      1180416   // 384
#define WS_W2BF    1180800   // bf16[384*768] lives here

// bank-balanced 16B-chunk swizzle: chunk idx mod 8 is bijective per 8-row group
#define SWZ(row,c) (((row)<<2) + ((c) ^ (((row)>>1)&3)))

__device__ __forceinline__ bf16x8 cvt8(float4 a, float4 b) {
  bf16x8 v;
  v[0]=(__bf16)a.x; v[1]=(__bf16)a.y; v[2]=(__bf16)a.z; v[3]=(__bf16)a.w;
  v[4]=(__bf16)b.x; v[5]=(__bf16)b.y; v[6]=(__bf16)b.z; v[7]=(__bf16)b.w;
  return v;
}

// K1: build all_reps (f32) rows 0..383 and W2bf (bf16) rows 384..767
__global__ __launch_bounds__(256) void k_build(
    const float* __restrict__ seq, const float* __restrict__ spk_emb,
    const float* __restrict__ dummy, const float* __restrict__ W2,
    const int* __restrict__ seg, const int* __restrict__ mstart,
    const int* __restrict__ mend, const int* __restrict__ spk_ids,
    float* __restrict__ all_reps, __bf16* __restrict__ W2bf) {
  int r = blockIdx.x, t = threadIdx.x;
  if (r < 384) {
    if (r == 0) {
      #pragma unroll
      for (int e = 0; e < 3; ++e) { int k = t + 256*e; all_reps[k] = dummy[k]; }
    } else {
      int m = r - 1;
      int sg = seg[m], st = mstart[m], en = mend[m];
      int sp = spk_ids[sg*512 + st];
      const float* p1 = seq + (size_t)(sg*512 + st)*768;
      const float* p2 = seq + (size_t)(sg*512 + en)*768;
      const float* p3 = spk_emb + (size_t)sp*768;
      #pragma unroll
      for (int e = 0; e < 3; ++e) { int k = t + 256*e; all_reps[r*768+k] = p1[k]+p2[k]+p3[k]; }
    }
  } else {
    int h = r - 384;
    #pragma unroll
    for (int e = 0; e < 3; ++e) { int k = t + 256*e; W2bf[h*768+k] = (__bf16)W2[h*768+k]; }
  }
}

// K2: C = reps(384x768) @ Bop(768x2304); Bop columns: [A(768) | Bm(768) | m1(384) | c1(384)]
// 64x128 tiles, grid (18,6)=108 blocks, 256 thr (4 waves 2x2: wave 32x64), BK=32
__global__ __launch_bounds__(256) void k_gemmB(
    const float* __restrict__ reps, const float* __restrict__ W1,
    const float* __restrict__ Wm1, const float* __restrict__ Wc1,
    const float* __restrict__ b1, const float* __restrict__ bm1, const float* __restrict__ bc1,
    float* __restrict__ Aprime, float* __restrict__ Bmat,
    float* __restrict__ relu_m1, float* __restrict__ relu_c1) {
  __shared__ bf16x8 lA[256];   // 64 rows x 4 chunks
  __shared__ bf16x8 lB[512];   // 128 rows x 4 chunks
  int nt = blockIdx.x;
  int m0 = blockIdx.y * 64;
  int t = threadIdx.x;
  const float* src; int stride, coloff;
  if (nt < 6)       { src = W1  + (size_t)(nt*128)*1536;      stride = 1536; coloff = 0;   }
  else if (nt < 12) { src = W1  + (size_t)((nt-6)*128)*1536;  stride = 1536; coloff = 768; }
  else if (nt < 15) { src = Wm1 + (size_t)((nt-12)*128)*768;  stride = 768;  coloff = 0;   }
  else              { src = Wc1 + (size_t)((nt-15)*128)*768;  stride = 768;  coloff = 0;   }

  int w = t>>6, l = t&63;
  int wm = w&1, wn = w>>1;
  int lr = l&15, lg = l>>4;

  int p = t>>2, q = t&3;
  const float* pa  = reps + (size_t)(m0+p)*768 + q*8;
  const float* pb0 = src + (size_t)p*stride + coloff + q*8;
  const float* pb1 = src + (size_t)(p+64)*stride + coloff + q*8;
  int ia  = SWZ(p, q);
  int ib0 = SWZ(p, q);
  int ib1 = SWZ(p+64, q);

  f32x4 acc[2][4] = {};

  for (int ks = 0; ks < 24; ++ks) {
    int k0 = ks*32;
    float4 a0 = *(const float4*)(pa + k0);
    float4 a1 = *(const float4*)(pa + k0 + 4);
    float4 b0 = *(const float4*)(pb0 + k0);
    float4 b1v = *(const float4*)(pb0 + k0 + 4);
    float4 c0 = *(const float4*)(pb1 + k0);
    float4 c1v = *(const float4*)(pb1 + k0 + 4);
    lA[ia]  = cvt8(a0, a1);
    lB[ib0] = cvt8(b0, b1v);
    lB[ib1] = cvt8(c0, c1v);
    __syncthreads();
    bf16x8 af[2], bfr[4];
    #pragma unroll
    for (int fa = 0; fa < 2; ++fa) { int row = wm*32 + fa*16 + lr; af[fa] = lA[SWZ(row, lg)]; }
    #pragma unroll
    for (int fb = 0; fb < 4; ++fb) { int row = wn*64 + fb*16 + lr; bfr[fb] = lB[SWZ(row, lg)]; }
    #pragma unroll
    for (int fa = 0; fa < 2; ++fa)
      #pragma unroll
      for (int fb = 0; fb < 4; ++fb)
        acc[fa][fb] = __builtin_amdgcn_mfma_f32_16x16x32_bf16(af[fa], bfr[fb], acc[fa][fb], 0, 0, 0);
    __syncthreads();
  }

  #pragma unroll
  for (int fa = 0; fa < 2; ++fa) {
    #pragma unroll
    for (int fb = 0; fb < 4; ++fb) {
      #pragma unroll
      for (int reg = 0; reg < 4; ++reg) {
        int m = m0 + wm*32 + fa*16 + lg*4 + reg;
        int nl = wn*64 + fb*16 + lr;
        float v = acc[fa][fb][reg];
        if (nt < 6)       { int n = nt*128 + nl;      Aprime[m*768+n]  = v + b1[n]; }
        else if (nt < 12) { int n = (nt-6)*128 + nl;  Bmat[m*768+n]    = v; }
        else if (nt < 15) { int n = (nt-12)*128 + nl; relu_m1[m*384+n] = fmaxf(v + bm1[n], 0.f); }
        else              { int n = (nt-15)*128 + nl; relu_c1[m*384+n] = fmaxf(v + bc1[n], 0.f); }
      }
    }
  }
}

// K3: ms chain, 48 blocks x 8 rows, 192 threads (h dim)
__global__ __launch_bounds__(192) void k_ms(
    const float* __restrict__ relu_m1, const float* __restrict__ Wm2,
    const float* __restrict__ bm2, const float* __restrict__ Wm3,
    const float* __restrict__ bm3, float* __restrict__ ms) {
  __shared__ float x[8][384];
  __shared__ float part[8][3];
  int r0 = blockIdx.x*8, t = threadIdx.x;
  const float4* srcv = (const float4*)(relu_m1 + (size_t)r0*384);
  float4* dstv = (float4*)&x[0][0];
  #pragma unroll
  for (int e = 0; e < 4; ++e) dstv[t + 192*e] = srcv[t + 192*e];
  __syncthreads();
  float a[8] = {};
  const float4* wv = (const float4*)(Wm2 + (size_t)t*384);
  for (int k = 0; k < 96; ++k) {
    float4 wq = wv[k];
    #pragma unroll
    for (int r = 0; r < 8; ++r) {
      float4 xq = *(const float4*)&x[r][k*4];
      a[r] += wq.x*xq.x + wq.y*xq.y + wq.z*xq.z + wq.w*xq.w;
    }
  }
  float wm3 = Wm3[t], bb = bm2[t];
  #pragma unroll
  for (int r = 0; r < 8; ++r) {
    float c = fmaxf(a[r] + bb, 0.f) * wm3;
    c += __shfl_xor(c, 1);  c += __shfl_xor(c, 2);  c += __shfl_xor(c, 4);
    c += __shfl_xor(c, 8);  c += __shfl_xor(c, 16); c += __shfl_xor(c, 32);
    if ((t&63) == 0) part[r][t>>6] = c;
  }
  __syncthreads();
  if (t < 8) ms[r0+t] = part[t][0] + part[t][1] + part[t][2] + bm3[0];
}

// K4: pair scores, exact lower-triangle 1D grid (600 blocks).
// Tile 128 pairs (16i x 8j) x 384 h, K=768 in 24 steps of 32.
// Double-buffered LDS, 1 barrier/K-step; prefetch issued right after barrier.
__global__ __launch_bounds__(512) void k_pair(
    const float* __restrict__ Aprime, const float* __restrict__ Bmat,
    const __bf16* __restrict__ W2bf, const float* __restrict__ b2,
    const float* __restrict__ w3, const float* __restrict__ b3,
    const float* __restrict__ ms, const int* __restrict__ lfirst,
    float* __restrict__ Ssum, float* __restrict__ Pf) {
  int bid = blockIdx.x;
  // bid = ib*(ib+1) + jb, jb in [0, 2ib+1]
  int ib = (int)((__fsqrt_rn(4.0f*bid + 1.0f) - 1.0f) * 0.5f);
  while ((ib+1)*(ib+2) <= bid) ++ib;
  while (ib*(ib+1) > bid) --ib;
  int jb = bid - ib*(ib+1);
  int i0 = ib*16, j0 = jb*8;

  __shared__ bf16x8 lA[2][512];    // h1 tile [128p][32k], swizzled 16B chunks
  __shared__ bf16x8 lB[2][1536];   // W2 tile [384h][32k]
  __shared__ float score_lds[128][4];

  int t = threadIdx.x;
  int w = t>>6, l = t&63;
  int wp = w&1, wh = w>>1;
  int lr = l&15, lg = l>>4;

  int p = t>>2, q = t&3;
  const float* pArow = Aprime + (size_t)(j0 + (p&7))*768 + q*8;
  const float* pBrow = Bmat   + (size_t)(i0 + (p>>3))*768 + q*8;
  const __bf16* pW0 = W2bf + (size_t)p*768       + q*8;
  const __bf16* pW1 = W2bf + (size_t)(p+128)*768 + q*8;
  const __bf16* pW2p = W2bf + (size_t)(p+256)*768 + q*8;
  int idxH  = SWZ(p, q);
  int idxW0 = SWZ(p, q);
  int idxW1 = SWZ(p+128, q);
  int idxW2 = SWZ(p+256, q);

  float4 ga0, ga1, gb0, gb1;
  bf16x8 gw0, gw1, gw2;

  #define LOADG(k0) { \
    ga0 = *(const float4*)(pArow + (k0)); \
    ga1 = *(const float4*)(pArow + (k0) + 4); \
    gb0 = *(const float4*)(pBrow + (k0)); \
    gb1 = *(const float4*)(pBrow + (k0) + 4); \
    gw0 = *(const bf16x8*)(pW0  + (k0)); \
    gw1 = *(const bf16x8*)(pW1  + (k0)); \
    gw2 = *(const bf16x8*)(pW2p + (k0)); }

  #define WRITEB(buf) { \
    float4 r0, r1; \
    r0.x = fmaxf(ga0.x + gb0.x, 0.f); r0.y = fmaxf(ga0.y + gb0.y, 0.f); \
    r0.z = fmaxf(ga0.z + gb0.z, 0.f); r0.w = fmaxf(ga0.w + gb0.w, 0.f); \
    r1.x = fmaxf(ga1.x + gb1.x, 0.f); r1.y = fmaxf(ga1.y + gb1.y, 0.f); \
    r1.z = fmaxf(ga1.z + gb1.z, 0.f); r1.w = fmaxf(ga1.w + gb1.w, 0.f); \
    lA[buf][idxH]  = cvt8(r0, r1); \
    lB[buf][idxW0] = gw0; lB[buf][idxW1] = gw1; lB[buf][idxW2] = gw2; }

  // prologue: stage tile 0
  LOADG(0);
  WRITEB(0);

  f32x4 acc[4][6] = {};
  int cur = 0;

  for (int ks = 0; ks < 24; ++ks) {
    __syncthreads();                 // buf[cur] ready
    if (ks < 23) LOADG((ks+1)*32);   // latency hides under ds_read + MFMA
    bf16x8 af[4], bfr[6];
    #pragma unroll
    for (int fp = 0; fp < 4; ++fp) { int row = wp*64 + fp*16 + lr; af[fp] = lA[cur][SWZ(row, lg)]; }
    #pragma unroll
    for (int fh = 0; fh < 6; ++fh) { int row = wh*96 + fh*16 + lr; bfr[fh] = lB[cur][SWZ(row, lg)]; }
    __builtin_amdgcn_s_setprio(1);
    #pragma unroll
    for (int fp = 0; fp < 4; ++fp)
      #pragma unroll
      for (int fh = 0; fh < 6; ++fh)
        acc[fp][fh] = __builtin_amdgcn_mfma_f32_16x16x32_bf16(af[fp], bfr[fh], acc[fp][fh], 0, 0, 0);
    __builtin_amdgcn_s_setprio(0);
    if (ks < 23) WRITEB(cur^1);      // vmcnt wait lands here, after MFMA phase
    cur ^= 1;
  }

  // epilogue 1: s_p += w3[h]*relu(C2 + b2[h]) over this wave's 96 h
  float sacc[4][4] = {};
  #pragma unroll
  for (int fh = 0; fh < 6; ++fh) {
    int hcol = wh*96 + fh*16 + lr;
    float bb = b2[hcol], ww = w3[hcol];
    #pragma unroll
    for (int fp = 0; fp < 4; ++fp)
      #pragma unroll
      for (int reg = 0; reg < 4; ++reg)
        sacc[fp][reg] += fmaxf(acc[fp][fh][reg] + bb, 0.f) * ww;
  }
  #pragma unroll
  for (int fp = 0; fp < 4; ++fp) {
    #pragma unroll
    for (int reg = 0; reg < 4; ++reg) {
      float v = sacc[fp][reg];
      v += __shfl_xor(v, 1); v += __shfl_xor(v, 2);
      v += __shfl_xor(v, 4); v += __shfl_xor(v, 8);
      if (lr == 0) score_lds[wp*64 + fp*16 + lg*4 + reg][wh] = v;
    }
  }
  __syncthreads();

  // epilogue 2: combine 4 h-waves, add b3, exp-sum per row i, pick Pf
  if (t < 128) {
    int pp = t;
    float s = score_lds[pp][0] + score_lds[pp][1] + score_lds[pp][2] + score_lds[pp][3] + b3[0];
    int i = i0 + (pp>>3), j = j0 + (pp&7);
    float e = 0.f;
    if (j < i) {
      float sm = s + ms[j];
      e = __expf(sm);
      if (j == lfirst[i-1]) Pf[i] = sm;
    }
    e += __shfl_xor(e, 1); e += __shfl_xor(e, 2); e += __shfl_xor(e, 4);
    if ((t&7) == 0) atomicAdd(&Ssum[i], e);
  }
}

// K5: char CE
__global__ __launch_bounds__(64) void k_ce(
    const float* __restrict__ relu_c1, const float* __restrict__ Wc2,
    const float* __restrict__ bc2, const int* __restrict__ label,
    float* __restrict__ out) {
  __shared__ float lg[18];
  int m = blockIdx.x, t = threadIdx.x;
  if (t < 18) {
    const float4* xv = (const float4*)(relu_c1 + (size_t)(m+1)*384);
    const float4* wv = (const float4*)(Wc2 + (size_t)t*384);
    float d = 0.f;
    for (int k = 0; k < 96; ++k) {
      float4 a = xv[k], b = wv[k];
      d += a.x*b.x + a.y*b.y + a.z*b.z + a.w*b.w;
    }
    lg[t] = d + bc2[t];
  }
  __syncthreads();
  if (t == 0) {
    float sum = 0.f;
    for (int c = 0; c < 18; ++c) sum += __expf(lg[c]);
    atomicAdd(out, __logf(sum) - lg[label[m]]);
  }
}

// K6: nll reduce
__global__ __launch_bounds__(384) void k_nll(
    const float* __restrict__ Ssum, const float* __restrict__ Pf,
    float* __restrict__ out) {
  int i = threadIdx.x;
  if (i >= 1) atomicAdd(out, __logf(Ssum[i]) - Pf[i]);
}

extern "C" void kernel_launch(void* const* d_in, const int* in_sizes, int n_in,
                              void* d_out, int out_size, void* d_ws, size_t ws_size,
                              hipStream_t stream) {
  (void)in_sizes; (void)n_in; (void)out_size; (void)ws_size;
  const float* seq   = (const float*)d_in[0];
  const float* spk   = (const float*)d_in[1];
  const float* dummy = (const float*)d_in[2];
  const float* W1    = (const float*)d_in[3];
  const float* b1    = (const float*)d_in[4];
  const float* W2    = (const float*)d_in[5];
  const float* b2    = (const float*)d_in[6];
  const float* W3    = (const float*)d_in[7];
  const float* b3    = (const float*)d_in[8];
  const float* Wm1   = (const float*)d_in[9];
  const float* bm1   = (const float*)d_in[10];
  const float* Wm2   = (const float*)d_in[11];
  const float* bm2   = (const float*)d_in[12];
  const float* Wm3   = (const float*)d_in[13];
  const float* bm3   = (const float*)d_in[14];
  const float* Wc1   = (const float*)d_in[15];
  const float* bc1   = (const float*)d_in[16];
  const float* Wc2   = (const float*)d_in[17];
  const float* bc2   = (const float*)d_in[18];
  const int* seg     = (const int*)d_in[19];
  const int* mstart  = (const int*)d_in[20];
  const int* mend    = (const int*)d_in[21];
  const int* spk_ids = (const int*)d_in[22];
  const int* lfirst  = (const int*)d_in[23];
  const int* clabel  = (const int*)d_in[25];

  float* ws = (float*)d_ws;
  float* all_reps = ws + WS_ALLREPS;
  float* Aprime   = ws + WS_APRIME;
  float* Bmat     = ws + WS_BMAT;
  float* relu_m1  = ws + WS_RELUM1;
  float* relu_c1  = ws + WS_RELUC1;
  float* msv      = ws + WS_MS;
  float* Ssum     = ws + WS_SSUM;
  float* Pf       = ws + WS_PF;
  __bf16* W2bf    = (__bf16*)(ws + WS_W2BF);
  float* out      = (float*)d_out;

  hipMemsetAsync(out, 0, sizeof(float), stream);
  hipMemsetAsync(Ssum, 0, 384*sizeof(float), stream);

  k_build<<<768, 256, 0, stream>>>(seq, spk, dummy, W2, seg, mstart, mend, spk_ids, all_reps, W2bf);
  k_gemmB<<<dim3(18,6), 256, 0, stream>>>(all_reps, W1, Wm1, Wc1, b1, bm1, bc1, Aprime, Bmat, relu_m1, relu_c1);
  k_ms<<<48, 192, 0, stream>>>(relu_m1, Wm2, bm2, Wm3, bm3, msv);
  k_pair<<<600, 512, 0, stream>>>(Aprime, Bmat, W2bf, b2, W3, b3, msv, lfirst, Ssum, Pf);
  k_ce<<<383, 64, 0, stream>>>(relu_c1, Wc2, bc2, clabel, out);
  k_nll<<<1, 384, 0, stream>>>(Ssum, Pf, out);
}

// Round 4
// 246.849 us; speedup vs baseline: 1.1418x; 1.0582x over previous
//
#include <hip/hip_runtime.h>

typedef __bf16 bf16x8 __attribute__((ext_vector_type(8)));
typedef float f32x4 __attribute__((ext_vector_type(4)));

// ---------------- ws layout (float offsets) ----------------
#define WS_ALLREPS 0         // 384*768
#define WS_APRIME  294912    // 384*768  (A + b_pair1)
#define WS_BMAT    589824    // 384*768
#define WS_RELUM1  884736    // 384*384
#define WS_RELUC1  1032192   // 384*384
#define WS_MS      1179648   // 384
#define WS_W2BF    1180032   // bf16[384*768] = 147456 floats
#define WS_S       1327488   // 2 * 600*128 f32 partial scores

// bank-balanced 16B-chunk swizzle: chunk idx mod 8 bijective per 8-row group
#define SWZ(row,c) (((row)<<2) + ((c) ^ (((row)>>1)&3)))

__device__ __forceinline__ bf16x8 cvt8(float4 a, float4 b) {
  bf16x8 v;
  v[0]=(__bf16)a.x; v[1]=(__bf16)a.y; v[2]=(__bf16)a.z; v[3]=(__bf16)a.w;
  v[4]=(__bf16)b.x; v[5]=(__bf16)b.y; v[6]=(__bf16)b.z; v[7]=(__bf16)b.w;
  return v;
}

// K1: build all_reps rows 0..383, W2bf rows 384..767; block 0 zeroes out
__global__ __launch_bounds__(256) void k_build(
    const float* __restrict__ seq, const float* __restrict__ spk_emb,
    const float* __restrict__ dummy, const float* __restrict__ W2,
    const int* __restrict__ seg, const int* __restrict__ mstart,
    const int* __restrict__ mend, const int* __restrict__ spk_ids,
    float* __restrict__ all_reps, __bf16* __restrict__ W2bf,
    float* __restrict__ out) {
  int r = blockIdx.x, t = threadIdx.x;
  if (r < 384) {
    if (r == 0) {
      if (t == 0) out[0] = 0.f;
      #pragma unroll
      for (int e = 0; e < 3; ++e) { int k = t + 256*e; all_reps[k] = dummy[k]; }
    } else {
      int m = r - 1;
      int sg = seg[m], st = mstart[m], en = mend[m];
      int sp = spk_ids[sg*512 + st];
      const float* p1 = seq + (size_t)(sg*512 + st)*768;
      const float* p2 = seq + (size_t)(sg*512 + en)*768;
      const float* p3 = spk_emb + (size_t)sp*768;
      #pragma unroll
      for (int e = 0; e < 3; ++e) { int k = t + 256*e; all_reps[r*768+k] = p1[k]+p2[k]+p3[k]; }
    }
  } else {
    int h = r - 384;
    #pragma unroll
    for (int e = 0; e < 3; ++e) { int k = t + 256*e; W2bf[h*768+k] = (__bf16)W2[h*768+k]; }
  }
}

// K2: C = reps(384x768) @ [A|Bm|m1|c1](768x2304); 64x128 tiles, dbuf LDS
__global__ __launch_bounds__(256) void k_gemmB(
    const float* __restrict__ reps, const float* __restrict__ W1,
    const float* __restrict__ Wm1, const float* __restrict__ Wc1,
    const float* __restrict__ b1, const float* __restrict__ bm1, const float* __restrict__ bc1,
    float* __restrict__ Aprime, float* __restrict__ Bmat,
    float* __restrict__ relu_m1, float* __restrict__ relu_c1) {
  __shared__ bf16x8 lA[2][256];   // 64 rows x 4 chunks
  __shared__ bf16x8 lB[2][512];   // 128 rows x 4 chunks
  int nt = blockIdx.x;
  int m0 = blockIdx.y * 64;
  int t = threadIdx.x;
  const float* src; int stride, coloff;
  if (nt < 6)       { src = W1  + (size_t)(nt*128)*1536;      stride = 1536; coloff = 0;   }
  else if (nt < 12) { src = W1  + (size_t)((nt-6)*128)*1536;  stride = 1536; coloff = 768; }
  else if (nt < 15) { src = Wm1 + (size_t)((nt-12)*128)*768;  stride = 768;  coloff = 0;   }
  else              { src = Wc1 + (size_t)((nt-15)*128)*768;  stride = 768;  coloff = 0;   }

  int w = t>>6, l = t&63;
  int wm = w&1, wn = w>>1;
  int lr = l&15, lg = l>>4;

  int p = t>>2, q = t&3;
  const float* pa  = reps + (size_t)(m0+p)*768 + q*8;
  const float* pb0 = src + (size_t)p*stride + coloff + q*8;
  const float* pb1 = src + (size_t)(p+64)*stride + coloff + q*8;
  int ia  = SWZ(p, q);
  int ib0 = SWZ(p, q);
  int ib1 = SWZ(p+64, q);

  float4 a0, a1, b0, b1v, c0, c1v;
  #define G_LOADG(k0) { \
    a0  = *(const float4*)(pa  + (k0)); a1  = *(const float4*)(pa  + (k0) + 4); \
    b0  = *(const float4*)(pb0 + (k0)); b1v = *(const float4*)(pb0 + (k0) + 4); \
    c0  = *(const float4*)(pb1 + (k0)); c1v = *(const float4*)(pb1 + (k0) + 4); }
  #define G_WRITEB(buf) { \
    lA[buf][ia]  = cvt8(a0, a1); \
    lB[buf][ib0] = cvt8(b0, b1v); \
    lB[buf][ib1] = cvt8(c0, c1v); }

  G_LOADG(0);
  G_WRITEB(0);

  f32x4 acc[2][4] = {};
  int cur = 0;

  for (int ks = 0; ks < 24; ++ks) {
    __syncthreads();
    if (ks < 23) G_LOADG((ks+1)*32);
    bf16x8 af[2], bfr[4];
    #pragma unroll
    for (int fa = 0; fa < 2; ++fa) { int row = wm*32 + fa*16 + lr; af[fa] = lA[cur][SWZ(row, lg)]; }
    #pragma unroll
    for (int fb = 0; fb < 4; ++fb) { int row = wn*64 + fb*16 + lr; bfr[fb] = lB[cur][SWZ(row, lg)]; }
    __builtin_amdgcn_s_setprio(1);
    #pragma unroll
    for (int fa = 0; fa < 2; ++fa)
      #pragma unroll
      for (int fb = 0; fb < 4; ++fb)
        acc[fa][fb] = __builtin_amdgcn_mfma_f32_16x16x32_bf16(af[fa], bfr[fb], acc[fa][fb], 0, 0, 0);
    __builtin_amdgcn_s_setprio(0);
    if (ks < 23) G_WRITEB(cur^1);
    cur ^= 1;
  }

  #pragma unroll
  for (int fa = 0; fa < 2; ++fa) {
    #pragma unroll
    for (int fb = 0; fb < 4; ++fb) {
      #pragma unroll
      for (int reg = 0; reg < 4; ++reg) {
        int m = m0 + wm*32 + fa*16 + lg*4 + reg;
        int nl = wn*64 + fb*16 + lr;
        float v = acc[fa][fb][reg];
        if (nt < 6)       { int n = nt*128 + nl;      Aprime[m*768+n]  = v + b1[n]; }
        else if (nt < 12) { int n = (nt-6)*128 + nl;  Bmat[m*768+n]    = v; }
        else if (nt < 15) { int n = (nt-12)*128 + nl; relu_m1[m*384+n] = fmaxf(v + bm1[n], 0.f); }
        else              { int n = (nt-15)*128 + nl; relu_c1[m*384+n] = fmaxf(v + bc1[n], 0.f); }
      }
    }
  }
}

// K3: ms chain, 192 blocks x 2 rows, 192 threads
__global__ __launch_bounds__(192) void k_ms(
    const float* __restrict__ relu_m1, const float* __restrict__ Wm2,
    const float* __restrict__ bm2, const float* __restrict__ Wm3,
    const float* __restrict__ bm3, float* __restrict__ ms) {
  __shared__ float x[2][384];
  __shared__ float part[2][3];
  int r0 = blockIdx.x*2, t = threadIdx.x;
  const float4* srcv = (const float4*)(relu_m1 + (size_t)r0*384);
  float4* dstv = (float4*)&x[0][0];
  dstv[t] = srcv[t];
  __syncthreads();
  float a[2] = {};
  const float4* wv = (const float4*)(Wm2 + (size_t)t*384);
  for (int k = 0; k < 96; ++k) {
    float4 wq = wv[k];
    #pragma unroll
    for (int r = 0; r < 2; ++r) {
      float4 xq = *(const float4*)&x[r][k*4];
      a[r] += wq.x*xq.x + wq.y*xq.y + wq.z*xq.z + wq.w*xq.w;
    }
  }
  float wm3 = Wm3[t], bb = bm2[t];
  #pragma unroll
  for (int r = 0; r < 2; ++r) {
    float c = fmaxf(a[r] + bb, 0.f) * wm3;
    c += __shfl_xor(c, 1);  c += __shfl_xor(c, 2);  c += __shfl_xor(c, 4);
    c += __shfl_xor(c, 8);  c += __shfl_xor(c, 16); c += __shfl_xor(c, 32);
    if ((t&63) == 0) part[r][t>>6] = c;
  }
  __syncthreads();
  if (t < 2) ms[r0+t] = part[t][0] + part[t][1] + part[t][2] + bm3[0];
}

// K4: pair partial scores. Grid (600 tiles, 2 h-halves), 256 thr (4 waves 2p x 2h).
// Block: 128 pairs (16i x 8j) x 192 h, K=768 in 24 steps of 32. 2 blocks/CU.
__global__ __launch_bounds__(256, 2) void k_pair(
    const float* __restrict__ Aprime, const float* __restrict__ Bmat,
    const __bf16* __restrict__ W2bf, const float* __restrict__ b2,
    const float* __restrict__ w3,
    float* __restrict__ S) {
  int bid = blockIdx.x;
  int hh = blockIdx.y;
  int h0 = hh * 192;
  // bid = ib*(ib+1) + jb, jb in [0, 2ib+1]
  int ib = (int)((__fsqrt_rn(4.0f*bid + 1.0f) - 1.0f) * 0.5f);
  while ((ib+1)*(ib+2) <= bid) ++ib;
  while (ib*(ib+1) > bid) --ib;
  int jb = bid - ib*(ib+1);
  int i0 = ib*16, j0 = jb*8;

  __shared__ bf16x8 lA[2][512];    // h1 tile [128p][32k]
  __shared__ bf16x8 lB[2][768];    // W2 tile [192h][32k]
  __shared__ float score_lds[128][2];

  int t = threadIdx.x;
  int w = t>>6, l = t&63;
  int wp = w&1, wh = w>>1;
  int lr = l&15, lg = l>>4;

  // lA staging: thread t stages 2 chunks: p = t>>1, q = qb, qb+1
  int p = t>>1, qb = (t&1)*2;
  const float* pArow = Aprime + (size_t)(j0 + (p&7))*768 + qb*8;
  const float* pBrow = Bmat   + (size_t)(i0 + (p>>3))*768 + qb*8;
  int idxA0 = SWZ(p, qb), idxA1 = SWZ(p, qb+1);
  // lB staging: 3 chunks c = t + 256e
  const __bf16* pW[3]; int idxW[3];
  #pragma unroll
  for (int e = 0; e < 3; ++e) {
    int c = t + 256*e, row = c>>2, qq = c&3;
    pW[e] = W2bf + (size_t)(h0 + row)*768 + qq*8;
    idxW[e] = SWZ(row, qq);
  }

  float4 ga0, ga1, ga2, ga3, gb0, gb1, gb2, gb3;
  bf16x8 gw0, gw1, gw2;

  #define LOADG(k0) { \
    ga0 = *(const float4*)(pArow + (k0));     ga1 = *(const float4*)(pArow + (k0) + 4); \
    ga2 = *(const float4*)(pArow + (k0) + 8); ga3 = *(const float4*)(pArow + (k0) + 12); \
    gb0 = *(const float4*)(pBrow + (k0));     gb1 = *(const float4*)(pBrow + (k0) + 4); \
    gb2 = *(const float4*)(pBrow + (k0) + 8); gb3 = *(const float4*)(pBrow + (k0) + 12); \
    gw0 = *(const bf16x8*)(pW[0] + (k0)); \
    gw1 = *(const bf16x8*)(pW[1] + (k0)); \
    gw2 = *(const bf16x8*)(pW[2] + (k0)); }

  #define WRITEB(buf) { \
    float4 r0, r1, r2, r3; \
    r0.x = fmaxf(ga0.x + gb0.x, 0.f); r0.y = fmaxf(ga0.y + gb0.y, 0.f); \
    r0.z = fmaxf(ga0.z + gb0.z, 0.f); r0.w = fmaxf(ga0.w + gb0.w, 0.f); \
    r1.x = fmaxf(ga1.x + gb1.x, 0.f); r1.y = fmaxf(ga1.y + gb1.y, 0.f); \
    r1.z = fmaxf(ga1.z + gb1.z, 0.f); r1.w = fmaxf(ga1.w + gb1.w, 0.f); \
    r2.x = fmaxf(ga2.x + gb2.x, 0.f); r2.y = fmaxf(ga2.y + gb2.y, 0.f); \
    r2.z = fmaxf(ga2.z + gb2.z, 0.f); r2.w = fmaxf(ga2.w + gb2.w, 0.f); \
    r3.x = fmaxf(ga3.x + gb3.x, 0.f); r3.y = fmaxf(ga3.y + gb3.y, 0.f); \
    r3.z = fmaxf(ga3.z + gb3.z, 0.f); r3.w = fmaxf(ga3.w + gb3.w, 0.f); \
    lA[buf][idxA0] = cvt8(r0, r1); \
    lA[buf][idxA1] = cvt8(r2, r3); \
    lB[buf][idxW[0]] = gw0; lB[buf][idxW[1]] = gw1; lB[buf][idxW[2]] = gw2; }

  LOADG(0);
  WRITEB(0);

  f32x4 acc[4][6] = {};
  int cur = 0;

  for (int ks = 0; ks < 24; ++ks) {
    __syncthreads();                 // buf[cur] ready
    if (ks < 23) LOADG((ks+1)*32);   // latency hides under ds_read + MFMA
    bf16x8 af[4], bfr[6];
    #pragma unroll
    for (int fp = 0; fp < 4; ++fp) { int row = wp*64 + fp*16 + lr; af[fp] = lA[cur][SWZ(row, lg)]; }
    #pragma unroll
    for (int fh = 0; fh < 6; ++fh) { int row = wh*96 + fh*16 + lr; bfr[fh] = lB[cur][SWZ(row, lg)]; }
    __builtin_amdgcn_s_setprio(1);
    #pragma unroll
    for (int fp = 0; fp < 4; ++fp)
      #pragma unroll
      for (int fh = 0; fh < 6; ++fh)
        acc[fp][fh] = __builtin_amdgcn_mfma_f32_16x16x32_bf16(af[fp], bfr[fh], acc[fp][fh], 0, 0, 0);
    __builtin_amdgcn_s_setprio(0);
    if (ks < 23) WRITEB(cur^1);      // vmcnt wait lands after MFMA phase
    cur ^= 1;
  }

  // epilogue: s_p += w3[h]*relu(C2 + b2[h]) over this wave's 96 h
  float sacc[4][4] = {};
  #pragma unroll
  for (int fh = 0; fh < 6; ++fh) {
    int hcol = h0 + wh*96 + fh*16 + lr;
    float bb = b2[hcol], ww = w3[hcol];
    #pragma unroll
    for (int fp = 0; fp < 4; ++fp)
      #pragma unroll
      for (int reg = 0; reg < 4; ++reg)
        sacc[fp][reg] += fmaxf(acc[fp][fh][reg] + bb, 0.f) * ww;
  }
  #pragma unroll
  for (int fp = 0; fp < 4; ++fp) {
    #pragma unroll
    for (int reg = 0; reg < 4; ++reg) {
      float v = sacc[fp][reg];
      v += __shfl_xor(v, 1); v += __shfl_xor(v, 2);
      v += __shfl_xor(v, 4); v += __shfl_xor(v, 8);
      if (lr == 0) score_lds[wp*64 + fp*16 + lg*4 + reg][wh] = v;
    }
  }
  __syncthreads();
  if (t < 128) {
    S[(size_t)hh*76800 + bid*128 + t] = score_lds[t][0] + score_lds[t][1];
  }
}

// K5: char CE
__global__ __launch_bounds__(64) void k_ce(
    const float* __restrict__ relu_c1, const float* __restrict__ Wc2,
    const float* __restrict__ bc2, const int* __restrict__ label,
    float* __restrict__ out) {
  __shared__ float lg[18];
  int m = blockIdx.x, t = threadIdx.x;
  if (t < 18) {
    const float4* xv = (const float4*)(relu_c1 + (size_t)(m+1)*384);
    const float4* wv = (const float4*)(Wc2 + (size_t)t*384);
    float d = 0.f;
    for (int k = 0; k < 96; ++k) {
      float4 a = xv[k], b = wv[k];
      d += a.x*b.x + a.y*b.y + a.z*b.z + a.w*b.w;
    }
    lg[t] = d + bc2[t];
  }
  __syncthreads();
  if (t == 0) {
    float sum = 0.f;
    for (int c = 0; c < 18; ++c) sum += __expf(lg[c]);
    atomicAdd(out, __logf(sum) - lg[label[m]]);
  }
}

// K6: per-row softmax epilogue + nll. 383 blocks (i=bid+1), 64 threads.
__global__ __launch_bounds__(64) void k_epi(
    const float* __restrict__ S, const float* __restrict__ ms,
    const float* __restrict__ b3, const int* __restrict__ lfirst,
    float* __restrict__ out) {
  int i = blockIdx.x + 1;
  int lane = threadIdx.x;
  int ibb = i >> 4, r = i & 15;
  int f = lfirst[i-1];
  float bb3 = b3[0];
  float esum = 0.f, smf = 0.f;
  for (int j = lane; j < i; j += 64) {
    int jbb = j >> 3;
    int idx = (ibb*(ibb+1) + jbb)*128 + r*8 + (j&7);
    float s = S[idx] + S[76800 + idx] + bb3 + ms[j];
    esum += __expf(s);
    if (j == f) smf = s;
  }
  esum += __shfl_xor(esum, 1);  esum += __shfl_xor(esum, 2);
  esum += __shfl_xor(esum, 4);  esum += __shfl_xor(esum, 8);
  esum += __shfl_xor(esum, 16); esum += __shfl_xor(esum, 32);
  smf += __shfl_xor(smf, 1);  smf += __shfl_xor(smf, 2);
  smf += __shfl_xor(smf, 4);  smf += __shfl_xor(smf, 8);
  smf += __shfl_xor(smf, 16); smf += __shfl_xor(smf, 32);
  if (lane == 0) atomicAdd(out, __logf(esum) - smf);
}

extern "C" void kernel_launch(void* const* d_in, const int* in_sizes, int n_in,
                              void* d_out, int out_size, void* d_ws, size_t ws_size,
                              hipStream_t stream) {
  (void)in_sizes; (void)n_in; (void)out_size; (void)ws_size;
  const float* seq   = (const float*)d_in[0];
  const float* spk   = (const float*)d_in[1];
  const float* dummy = (const float*)d_in[2];
  const float* W1    = (const float*)d_in[3];
  const float* b1    = (const float*)d_in[4];
  const float* W2    = (const float*)d_in[5];
  const float* b2    = (const float*)d_in[6];
  const float* W3    = (const float*)d_in[7];
  const float* b3    = (const float*)d_in[8];
  const float* Wm1   = (const float*)d_in[9];
  const float* bm1   = (const float*)d_in[10];
  const float* Wm2   = (const float*)d_in[11];
  const float* bm2   = (const float*)d_in[12];
  const float* Wm3   = (const float*)d_in[13];
  const float* bm3   = (const float*)d_in[14];
  const float* Wc1   = (const float*)d_in[15];
  const float* bc1   = (const float*)d_in[16];
  const float* Wc2   = (const float*)d_in[17];
  const float* bc2   = (const float*)d_in[18];
  const int* seg     = (const int*)d_in[19];
  const int* mstart  = (const int*)d_in[20];
  const int* mend    = (const int*)d_in[21];
  const int* spk_ids = (const int*)d_in[22];
  const int* lfirst  = (const int*)d_in[23];
  const int* clabel  = (const int*)d_in[25];

  float* ws = (float*)d_ws;
  float* all_reps = ws + WS_ALLREPS;
  float* Aprime   = ws + WS_APRIME;
  float* Bmat     = ws + WS_BMAT;
  float* relu_m1  = ws + WS_RELUM1;
  float* relu_c1  = ws + WS_RELUC1;
  float* msv      = ws + WS_MS;
  __bf16* W2bf    = (__bf16*)(ws + WS_W2BF);
  float* S        = ws + WS_S;
  float* out      = (float*)d_out;

  k_build<<<768, 256, 0, stream>>>(seq, spk, dummy, W2, seg, mstart, mend, spk_ids, all_reps, W2bf, out);
  k_gemmB<<<dim3(18,6), 256, 0, stream>>>(all_reps, W1, Wm1, Wc1, b1, bm1, bc1, Aprime, Bmat, relu_m1, relu_c1);
  k_ms<<<192, 192, 0, stream>>>(relu_m1, Wm2, bm2, Wm3, bm3, msv);
  k_pair<<<dim3(600,2), 256, 0, stream>>>(Aprime, Bmat, W2bf, b2, W3, S);
  k_ce<<<383, 64, 0, stream>>>(relu_c1, Wc2, bc2, clabel, out);
  k_epi<<<383, 64, 0, stream>>>(S, msv, b3, lfirst, out);
}

// Round 6
// 240.195 us; speedup vs baseline: 1.1734x; 1.0277x over previous
//
#include <hip/hip_runtime.h>

typedef __bf16 bf16x8 __attribute__((ext_vector_type(8)));
typedef float f32x4 __attribute__((ext_vector_type(4)));

// ---------------- ws layout (float offsets) ----------------
// S overlaps ALLREPS: all_reps is dead before k_mega writes S.
#define WS_S       0         // 4 slabs * 75264 = 301056
#define WS_ALLREPS 0         // 294912 (k_build -> k_gemmB only)
#define WS_APRIME  301056    // 384*768 f32
#define WS_BMAT    595968    // 384*768 f32
#define WS_RELUM1  890880    // 384*384 f32
#define WS_RELUC1  1038336   // 384*384 f32
#define WS_MS      1185792   // 384
#define WS_W2BF    1186176   // bf16[384*768] = 147456 f32-words

#define NPAIR 2352           // 1176 tiles * 2 hh
#define NMS   384
#define NCE   383
#define SLAB  75264          // 1176*64

// bank-balanced 16B-chunk swizzle: chunk idx mod 8 bijective per 8-row group
#define SWZ(row,c) (((row)<<2) + ((c) ^ (((row)>>1)&3)))

__device__ __forceinline__ bf16x8 cvt8(float4 a, float4 b) {
  bf16x8 v;
  v[0]=(__bf16)a.x; v[1]=(__bf16)a.y; v[2]=(__bf16)a.z; v[3]=(__bf16)a.w;
  v[4]=(__bf16)b.x; v[5]=(__bf16)b.y; v[6]=(__bf16)b.z; v[7]=(__bf16)b.w;
  return v;
}

// K1: build all_reps (f32) rows 0..383 and W2bf (bf16) rows 384..767
__global__ __launch_bounds__(256) void k_build(
    const float* __restrict__ seq, const float* __restrict__ spk_emb,
    const float* __restrict__ dummy, const float* __restrict__ W2,
    const int* __restrict__ seg, const int* __restrict__ mstart,
    const int* __restrict__ mend, const int* __restrict__ spk_ids,
    float* __restrict__ all_reps, __bf16* __restrict__ W2bf,
    float* __restrict__ out) {
  int r = blockIdx.x, t = threadIdx.x;
  if (r < 384) {
    if (r == 0) {
      if (t == 0) out[0] = 0.f;
      #pragma unroll
      for (int e = 0; e < 3; ++e) { int k = t + 256*e; all_reps[k] = dummy[k]; }
    } else {
      int m = r - 1;
      int sg = seg[m], st = mstart[m], en = mend[m];
      int sp = spk_ids[sg*512 + st];
      const float* p1 = seq + (size_t)(sg*512 + st)*768;
      const float* p2 = seq + (size_t)(sg*512 + en)*768;
      const float* p3 = spk_emb + (size_t)sp*768;
      #pragma unroll
      for (int e = 0; e < 3; ++e) { int k = t + 256*e; all_reps[r*768+k] = p1[k]+p2[k]+p3[k]; }
    }
  } else {
    int h = r - 384;
    #pragma unroll
    for (int e = 0; e < 3; ++e) { int k = t + 256*e; W2bf[h*768+k] = (__bf16)W2[h*768+k]; }
  }
}

// K2: C = reps(384x768) @ [A|Bm|m1|c1](768x2304); 64x128 tiles, dbuf LDS
__global__ __launch_bounds__(256) void k_gemmB(
    const float* __restrict__ reps, const float* __restrict__ W1,
    const float* __restrict__ Wm1, const float* __restrict__ Wc1,
    const float* __restrict__ b1, const float* __restrict__ bm1, const float* __restrict__ bc1,
    float* __restrict__ Aprime, float* __restrict__ Bmat,
    float* __restrict__ relu_m1, float* __restrict__ relu_c1) {
  __shared__ bf16x8 lA[2][256];
  __shared__ bf16x8 lB[2][512];
  int nt = blockIdx.x;
  int m0 = blockIdx.y * 64;
  int t = threadIdx.x;
  const float* src; int stride, coloff;
  if (nt < 6)       { src = W1  + (size_t)(nt*128)*1536;      stride = 1536; coloff = 0;   }
  else if (nt < 12) { src = W1  + (size_t)((nt-6)*128)*1536;  stride = 1536; coloff = 768; }
  else if (nt < 15) { src = Wm1 + (size_t)((nt-12)*128)*768;  stride = 768;  coloff = 0;   }
  else              { src = Wc1 + (size_t)((nt-15)*128)*768;  stride = 768;  coloff = 0;   }

  int w = t>>6, l = t&63;
  int wm = w&1, wn = w>>1;
  int lr = l&15, lg = l>>4;

  int p = t>>2, q = t&3;
  const float* pa  = reps + (size_t)(m0+p)*768 + q*8;
  const float* pb0 = src + (size_t)p*stride + coloff + q*8;
  const float* pb1 = src + (size_t)(p+64)*stride + coloff + q*8;
  int ia  = SWZ(p, q);
  int ib0 = SWZ(p, q);
  int ib1 = SWZ(p+64, q);

  float4 a0, a1, b0, b1v, c0, c1v;
  #define G_LOADG(k0) { \
    a0  = *(const float4*)(pa  + (k0)); a1  = *(const float4*)(pa  + (k0) + 4); \
    b0  = *(const float4*)(pb0 + (k0)); b1v = *(const float4*)(pb0 + (k0) + 4); \
    c0  = *(const float4*)(pb1 + (k0)); c1v = *(const float4*)(pb1 + (k0) + 4); }
  #define G_WRITEB(buf) { \
    lA[buf][ia]  = cvt8(a0, a1); \
    lB[buf][ib0] = cvt8(b0, b1v); \
    lB[buf][ib1] = cvt8(c0, c1v); }

  G_LOADG(0);
  G_WRITEB(0);

  f32x4 acc[2][4] = {};
  int cur = 0;

  for (int ks = 0; ks < 24; ++ks) {
    __syncthreads();
    if (ks < 23) G_LOADG((ks+1)*32);
    bf16x8 af[2], bfr[4];
    #pragma unroll
    for (int fa = 0; fa < 2; ++fa) { int row = wm*32 + fa*16 + lr; af[fa] = lA[cur][SWZ(row, lg)]; }
    #pragma unroll
    for (int fb = 0; fb < 4; ++fb) { int row = wn*64 + fb*16 + lr; bfr[fb] = lB[cur][SWZ(row, lg)]; }
    __builtin_amdgcn_s_setprio(1);
    #pragma unroll
    for (int fa = 0; fa < 2; ++fa)
      #pragma unroll
      for (int fb = 0; fb < 4; ++fb)
        acc[fa][fb] = __builtin_amdgcn_mfma_f32_16x16x32_bf16(af[fa], bfr[fb], acc[fa][fb], 0, 0, 0);
    __builtin_amdgcn_s_setprio(0);
    if (ks < 23) G_WRITEB(cur^1);
    cur ^= 1;
  }

  #pragma unroll
  for (int fa = 0; fa < 2; ++fa) {
    #pragma unroll
    for (int fb = 0; fb < 4; ++fb) {
      #pragma unroll
      for (int reg = 0; reg < 4; ++reg) {
        int m = m0 + wm*32 + fa*16 + lg*4 + reg;
        int nl = wn*64 + fb*16 + lr;
        float v = acc[fa][fb][reg];
        if (nt < 6)       { int n = nt*128 + nl;      Aprime[m*768+n]  = v + b1[n]; }
        else if (nt < 12) { int n = (nt-6)*128 + nl;  Bmat[m*768+n]    = v; }
        else if (nt < 15) { int n = (nt-12)*128 + nl; relu_m1[m*384+n] = fmaxf(v + bm1[n], 0.f); }
        else              { int n = (nt-15)*128 + nl; relu_c1[m*384+n] = fmaxf(v + bc1[n], 0.f); }
      }
    }
  }
}

// K3 (mega): pair tiles (2-wave blocks) + ms rows + ce rows, all 128 threads.
__global__ __launch_bounds__(128, 2) void k_mega(
    const float* __restrict__ Aprime, const float* __restrict__ Bmat,
    const __bf16* __restrict__ W2bf, const float* __restrict__ b2,
    const float* __restrict__ w3, float* __restrict__ S,
    const float* __restrict__ relu_m1, const float* __restrict__ Wm2,
    const float* __restrict__ bm2, const float* __restrict__ Wm3,
    const float* __restrict__ bm3, float* __restrict__ msv,
    const float* __restrict__ relu_c1, const float* __restrict__ Wc2,
    const float* __restrict__ bc2, const int* __restrict__ label,
    float* __restrict__ out) {
  __shared__ char smem[32768];
  int bx = blockIdx.x, t = threadIdx.x;

  if (bx < NPAIR) {
    // ---------------- pair branch: 64 pairs (8i x 8j) x 192 h ----------------
    bf16x8 (*lA)[256] = (bf16x8 (*)[256])smem;            // h1 tile, dbuf
    bf16x8 (*lB)[768] = (bf16x8 (*)[768])(smem + 8192);   // W2 tile, dbuf
    int tile = bx >> 1, hh = bx & 1;
    int ib = (int)((__fsqrt_rn(8.0f*tile + 1.0f) - 1.0f) * 0.5f);
    while ((ib+1)*(ib+2)/2 <= tile) ++ib;
    while (ib*(ib+1)/2 > tile) --ib;
    int jb = tile - ib*(ib+1)/2;
    int i0 = ib*8, j0 = jb*8;
    int h0 = hh*192;

    int w = t>>6, l = t&63;
    int lr = l&15, lg = l>>4;

    // lA staging: thread t stages 2 chunks of row p
    int p = t>>1, qb = (t&1)*2;
    const float* pArow = Aprime + (size_t)(j0 + (p&7))*768 + qb*8;
    const float* pBrow = Bmat   + (size_t)(i0 + (p>>3))*768 + qb*8;
    int idxA0 = SWZ(p, qb), idxA1 = SWZ(p, qb+1);
    // lB staging: 6 chunks per thread
    const __bf16* pW[6]; int idxW[6];
    #pragma unroll
    for (int e = 0; e < 6; ++e) {
      int c6 = t + 128*e, row = c6>>2, qq = c6&3;
      pW[e] = W2bf + (size_t)(h0 + row)*768 + qq*8;
      idxW[e] = SWZ(row, qq);
    }

    float4 ga0, ga1, ga2, ga3, gb0, gb1, gb2, gb3;
    bf16x8 gw0, gw1, gw2, gw3, gw4, gw5;

    #define LOADG(k0) { \
      ga0 = *(const float4*)(pArow + (k0));     ga1 = *(const float4*)(pArow + (k0) + 4); \
      ga2 = *(const float4*)(pArow + (k0) + 8); ga3 = *(const float4*)(pArow + (k0) + 12); \
      gb0 = *(const float4*)(pBrow + (k0));     gb1 = *(const float4*)(pBrow + (k0) + 4); \
      gb2 = *(const float4*)(pBrow + (k0) + 8); gb3 = *(const float4*)(pBrow + (k0) + 12); \
      gw0 = *(const bf16x8*)(pW[0] + (k0)); gw1 = *(const bf16x8*)(pW[1] + (k0)); \
      gw2 = *(const bf16x8*)(pW[2] + (k0)); gw3 = *(const bf16x8*)(pW[3] + (k0)); \
      gw4 = *(const bf16x8*)(pW[4] + (k0)); gw5 = *(const bf16x8*)(pW[5] + (k0)); }

    #define WRITEB(buf) { \
      float4 r0, r1, r2, r3; \
      r0.x = fmaxf(ga0.x + gb0.x, 0.f); r0.y = fmaxf(ga0.y + gb0.y, 0.f); \
      r0.z = fmaxf(ga0.z + gb0.z, 0.f); r0.w = fmaxf(ga0.w + gb0.w, 0.f); \
      r1.x = fmaxf(ga1.x + gb1.x, 0.f); r1.y = fmaxf(ga1.y + gb1.y, 0.f); \
      r1.z = fmaxf(ga1.z + gb1.z, 0.f); r1.w = fmaxf(ga1.w + gb1.w, 0.f); \
      r2.x = fmaxf(ga2.x + gb2.x, 0.f); r2.y = fmaxf(ga2.y + gb2.y, 0.f); \
      r2.z = fmaxf(ga2.z + gb2.z, 0.f); r2.w = fmaxf(ga2.w + gb2.w, 0.f); \
      r3.x = fmaxf(ga3.x + gb3.x, 0.f); r3.y = fmaxf(ga3.y + gb3.y, 0.f); \
      r3.z = fmaxf(ga3.z + gb3.z, 0.f); r3.w = fmaxf(ga3.w + gb3.w, 0.f); \
      lA[buf][idxA0] = cvt8(r0, r1); \
      lA[buf][idxA1] = cvt8(r2, r3); \
      lB[buf][idxW[0]] = gw0; lB[buf][idxW[1]] = gw1; lB[buf][idxW[2]] = gw2; \
      lB[buf][idxW[3]] = gw3; lB[buf][idxW[4]] = gw4; lB[buf][idxW[5]] = gw5; }

    LOADG(0);
    WRITEB(0);

    f32x4 acc[4][6] = {};
    int cur = 0;

    for (int ks = 0; ks < 24; ++ks) {
      __syncthreads();                 // buf[cur] ready
      if (ks < 23) LOADG((ks+1)*32);   // latency hides under ds_read + MFMA
      bf16x8 af[4], bfr[6];
      #pragma unroll
      for (int fp = 0; fp < 4; ++fp) { int row = fp*16 + lr; af[fp] = lA[cur][SWZ(row, lg)]; }
      #pragma unroll
      for (int fh = 0; fh < 6; ++fh) { int row = w*96 + fh*16 + lr; bfr[fh] = lB[cur][SWZ(row, lg)]; }
      __builtin_amdgcn_s_setprio(1);
      #pragma unroll
      for (int fp = 0; fp < 4; ++fp)
        #pragma unroll
        for (int fh = 0; fh < 6; ++fh)
          acc[fp][fh] = __builtin_amdgcn_mfma_f32_16x16x32_bf16(af[fp], bfr[fh], acc[fp][fh], 0, 0, 0);
      __builtin_amdgcn_s_setprio(0);
      if (ks < 23) WRITEB(cur^1);      // vmcnt wait lands after MFMA phase
      cur ^= 1;
    }

    // epilogue: partial score over this wave's 96 h, direct store to slab
    float sacc[4][4] = {};
    #pragma unroll
    for (int fh = 0; fh < 6; ++fh) {
      int hcol = h0 + w*96 + fh*16 + lr;
      float bb = b2[hcol], ww = w3[hcol];
      #pragma unroll
      for (int fp = 0; fp < 4; ++fp)
        #pragma unroll
        for (int reg = 0; reg < 4; ++reg)
          sacc[fp][reg] += fmaxf(acc[fp][fh][reg] + bb, 0.f) * ww;
    }
    float* Sp = S + (size_t)(hh*2 + w)*SLAB + tile*64;
    #pragma unroll
    for (int fp = 0; fp < 4; ++fp) {
      #pragma unroll
      for (int reg = 0; reg < 4; ++reg) {
        float v = sacc[fp][reg];
        v += __shfl_xor(v, 1); v += __shfl_xor(v, 2);
        v += __shfl_xor(v, 4); v += __shfl_xor(v, 8);
        if (lr == 0) Sp[fp*16 + lg*4 + reg] = v;
      }
    }
  } else if (bx < NPAIR + NMS) {
    // ---------------- ms branch: one mention row ----------------
    float* xs = (float*)smem;
    __shared__ float part[2];
    int r = bx - NPAIR;
    const float4* srcv = (const float4*)(relu_m1 + (size_t)r*384);
    if (t < 96) ((float4*)xs)[t] = srcv[t];
    __syncthreads();
    float d1 = 0.f, d2 = 0.f;
    const float4* w1v = (const float4*)(Wm2 + (size_t)t*384);
    const float4* w2v = (const float4*)(Wm2 + (size_t)(t+128 < 192 ? t+128 : t)*384);
    for (int k = 0; k < 96; ++k) {
      float4 xq = ((const float4*)xs)[k];
      float4 aq = w1v[k];
      d1 += aq.x*xq.x + aq.y*xq.y + aq.z*xq.z + aq.w*xq.w;
      if (t < 64) {
        float4 bq = w2v[k];
        d2 += bq.x*xq.x + bq.y*xq.y + bq.z*xq.z + bq.w*xq.w;
      }
    }
    float c = fmaxf(d1 + bm2[t], 0.f) * Wm3[t];
    if (t < 64) c += fmaxf(d2 + bm2[t+128], 0.f) * Wm3[t+128];
    c += __shfl_xor(c, 1);  c += __shfl_xor(c, 2);  c += __shfl_xor(c, 4);
    c += __shfl_xor(c, 8);  c += __shfl_xor(c, 16); c += __shfl_xor(c, 32);
    if ((t&63) == 0) part[t>>6] = c;
    __syncthreads();
    if (t == 0) msv[r] = part[0] + part[1] + bm3[0];
  } else {
    // ---------------- ce branch: one mention ----------------
    float* lg = (float*)smem;
    int m = bx - (NPAIR + NMS);
    if (t < 18) {
      const float4* xv = (const float4*)(relu_c1 + (size_t)(m+1)*384);
      const float4* wv = (const float4*)(Wc2 + (size_t)t*384);
      float d = 0.f;
      for (int k = 0; k < 96; ++k) {
        float4 a = xv[k], b = wv[k];
        d += a.x*b.x + a.y*b.y + a.z*b.z + a.w*b.w;
      }
      lg[t] = d + bc2[t];
    }
    __syncthreads();
    if (t == 0) {
      float sum = 0.f;
      for (int c = 0; c < 18; ++c) sum += __expf(lg[c]);
      atomicAdd(out, __logf(sum) - lg[label[m]]);
    }
  }
}

// K4: per-row softmax epilogue + nll. 383 blocks (i=bid+1), 64 threads.
__global__ __launch_bounds__(64) void k_epi(
    const float* __restrict__ S, const float* __restrict__ ms,
    const float* __restrict__ b3, const int* __restrict__ lfirst,
    float* __restrict__ out) {
  int i = blockIdx.x + 1;
  int lane = threadIdx.x;
  int ibb = i >> 3, r = i & 7;
  int f = lfirst[i-1];
  float bb3 = b3[0];
  float esum = 0.f, smf = 0.f;
  int tri = ibb*(ibb+1)/2;
  for (int j = lane; j < i; j += 64) {
    int jbb = j >> 3;
    int idx = (tri + jbb)*64 + r*8 + (j&7);
    float s = S[idx] + S[SLAB + idx] + S[2*SLAB + idx] + S[3*SLAB + idx] + bb3 + ms[j];
    esum += __expf(s);
    if (j == f) smf = s;
  }
  esum += __shfl_xor(esum, 1);  esum += __shfl_xor(esum, 2);
  esum += __shfl_xor(esum, 4);  esum += __shfl_xor(esum, 8);
  esum += __shfl_xor(esum, 16); esum += __shfl_xor(esum, 32);
  smf += __shfl_xor(smf, 1);  smf += __shfl_xor(smf, 2);
  smf += __shfl_xor(smf, 4);  smf += __shfl_xor(smf, 8);
  smf += __shfl_xor(smf, 16); smf += __shfl_xor(smf, 32);
  if (lane == 0) atomicAdd(out, __logf(esum) - smf);
}

extern "C" void kernel_launch(void* const* d_in, const int* in_sizes, int n_in,
                              void* d_out, int out_size, void* d_ws, size_t ws_size,
                              hipStream_t stream) {
  (void)in_sizes; (void)n_in; (void)out_size; (void)ws_size;
  const float* seq   = (const float*)d_in[0];
  const float* spk   = (const float*)d_in[1];
  const float* dummy = (const float*)d_in[2];
  const float* W1    = (const float*)d_in[3];
  const float* b1    = (const float*)d_in[4];
  const float* W2    = (const float*)d_in[5];
  const float* b2    = (const float*)d_in[6];
  const float* W3    = (const float*)d_in[7];
  const float* b3    = (const float*)d_in[8];
  const float* Wm1   = (const float*)d_in[9];
  const float* bm1   = (const float*)d_in[10];
  const float* Wm2   = (const float*)d_in[11];
  const float* bm2   = (const float*)d_in[12];
  const float* Wm3   = (const float*)d_in[13];
  const float* bm3   = (const float*)d_in[14];
  const float* Wc1   = (const float*)d_in[15];
  const float* bc1   = (const float*)d_in[16];
  const float* Wc2   = (const float*)d_in[17];
  const float* bc2   = (const float*)d_in[18];
  const int* seg     = (const int*)d_in[19];
  const int* mstart  = (const int*)d_in[20];
  const int* mend    = (const int*)d_in[21];
  const int* spk_ids = (const int*)d_in[22];
  const int* lfirst  = (const int*)d_in[23];
  const int* clabel  = (const int*)d_in[25];

  float* ws = (float*)d_ws;
  float* S        = ws + WS_S;
  float* all_reps = ws + WS_ALLREPS;
  float* Aprime   = ws + WS_APRIME;
  float* Bmat     = ws + WS_BMAT;
  float* relu_m1  = ws + WS_RELUM1;
  float* relu_c1  = ws + WS_RELUC1;
  float* msv      = ws + WS_MS;
  __bf16* W2bf    = (__bf16*)(ws + WS_W2BF);
  float* out      = (float*)d_out;

  k_build<<<768, 256, 0, stream>>>(seq, spk, dummy, W2, seg, mstart, mend, spk_ids, all_reps, W2bf, out);
  k_gemmB<<<dim3(18,6), 256, 0, stream>>>(all_reps, W1, Wm1, Wc1, b1, bm1, bc1, Aprime, Bmat, relu_m1, relu_c1);
  k_mega<<<NPAIR + NMS + NCE, 128, 0, stream>>>(Aprime, Bmat, W2bf, b2, W3, S,
                                                relu_m1, Wm2, bm2, Wm3, bm3, msv,
                                                relu_c1, Wc2, bc2, clabel, out);
  k_epi<<<383, 64, 0, stream>>>(S, msv, b3, lfirst, out);
}